// Round 2
// 631.868 us; speedup vs baseline: 1.1410x; 1.1410x over previous
//
#include <hip/hip_runtime.h>
#include <hip/hip_bf16.h>

typedef unsigned short u16;
typedef __attribute__((ext_vector_type(8))) __bf16 bf16x8;   // 4 VGPRs: MFMA A/B frag
typedef __attribute__((ext_vector_type(4))) float f32x4;     // MFMA C/D frag
typedef __attribute__((ext_vector_type(4))) float f4v;
typedef __attribute__((ext_vector_type(2))) unsigned short u16x2;
typedef __attribute__((ext_vector_type(4))) unsigned short u16x4;
typedef __attribute__((ext_vector_type(8))) unsigned short u16x8;

__device__ __forceinline__ u16 f32_to_bf16(float f) {
  unsigned int u = __builtin_bit_cast(unsigned int, f);
  u += 0x7FFFu + ((u >> 16) & 1u);   // RNE (inputs finite)
  return (u16)(u >> 16);
}

// fast gelu: v * sigmoid(1.59577*(v + 0.044715 v^3))  [tanh-form, max abs err ~3e-3]
__device__ __forceinline__ float fast_gelu(float v) {
  float v2 = v * v;
  float t = v * fmaf(0.0713548162726f, v2, 1.5957691216057308f);
  float e = __expf(-t);
  float s = __builtin_amdgcn_rcpf(1.0f + e);
  return v * s;
}

// async 16B global -> LDS (global_load_lds_dwordx4). LDS dest: wave-uniform base + lane*16.
__device__ __forceinline__ void async_ld16(const void* gsrc, void* ldst) {
  __builtin_amdgcn_global_load_lds(
      (__attribute__((address_space(1))) void*)(unsigned long long)gsrc,
      (__attribute__((address_space(3))) void*)(unsigned long long)ldst,
      16, 0, 0);
}

// ---------------- fp32 -> bf16 elementwise (x) ----------------
__global__ void cvt_kernel(const float* __restrict__ in, u16* __restrict__ out, int n8) {
  int i = blockIdx.x * blockDim.x + threadIdx.x;
  if (i >= n8) return;
  const f4v* p = (const f4v*)(in + (size_t)i * 8);
  f4v a = p[0], b = p[1];
  u16x8 r;
  r[0] = f32_to_bf16(a[0]); r[1] = f32_to_bf16(a[1]);
  r[2] = f32_to_bf16(a[2]); r[3] = f32_to_bf16(a[3]);
  r[4] = f32_to_bf16(b[0]); r[5] = f32_to_bf16(b[1]);
  r[6] = f32_to_bf16(b[2]); r[7] = f32_to_bf16(b[3]);
  *(u16x8*)(out + (size_t)i * 8) = r;
}

// ------------- fp32 [E][R][C] -> bf16 [E][C][R] (weight transpose) -------------
// 64x64 tile, 256 threads. float4 global reads (16B/lane), u16x4 global writes (8B/lane).
__global__ __launch_bounds__(256)
void tpose_cvt_kernel(const float* __restrict__ in, u16* __restrict__ out, int R, int C) {
  __shared__ u16 tile[64 * 66];  // stride 66: 4B-aligned u16x2 stores, spread banks
  const int e = blockIdx.z;
  const int c0 = blockIdx.x * 64, r0 = blockIdx.y * 64;
  const float* src = in + (size_t)e * R * C;
  u16* dst = out + (size_t)e * R * C;
  const int t = threadIdx.x;
#pragma unroll
  for (int i = 0; i < 4; ++i) {
    int idx = i * 256 + t;
    int row = idx >> 4, c4 = idx & 15;
    f4v v = *(const f4v*)&src[(size_t)(r0 + row) * C + (c0 + c4 * 4)];
    u16x2 lo, hi;
    lo[0] = f32_to_bf16(v[0]); lo[1] = f32_to_bf16(v[1]);
    hi[0] = f32_to_bf16(v[2]); hi[1] = f32_to_bf16(v[3]);
    *(u16x2*)&tile[row * 66 + c4 * 4] = lo;
    *(u16x2*)&tile[row * 66 + c4 * 4 + 2] = hi;
  }
  __syncthreads();
#pragma unroll
  for (int i = 0; i < 4; ++i) {
    int idx = i * 256 + t;
    int c = idx >> 4, r4 = idx & 15;
    u16x4 v;
#pragma unroll
    for (int j = 0; j < 4; ++j) v[j] = tile[(r4 * 4 + j) * 66 + c];
    *(u16x4*)&dst[(size_t)(c0 + c) * R + r0 + r4 * 4] = v;
  }
}

// ---------------- grouped GEMM: out[m][n] = A[m][:] . Bt[e][n][:] ----------------
// 256x256 tile, 8 waves (2Mx4N, per-wave 128x64), K sliced in 32-wide slices.
// Ring of 4 LDS slice-buffers (A 256x32 + B 256x32 each = 32KB; 128KB total).
// Deep pipeline (T3+T4+T5): compute slice s while s+1,s+2 are in flight and s+3
// is being issued -> s_waitcnt vmcnt(8) once per slice (never 0), raw s_barrier,
// setprio(1) around each 16-MFMA cluster. XOR-swizzled chunks (0 bank conflicts).
// XCD-aware 1D grid (slack slots land at the grid tail -> clean 256-block rounds).
// Requires (Mtot/256 + 8) % 8 == 0, K % 128 == 0, Nn % 256 == 0.
template <int FUSE>
__global__ __launch_bounds__(512, 2)
void grouped_gemm(const u16* __restrict__ A, const u16* __restrict__ Bt,
                  void* __restrict__ Out, const int* __restrict__ tokens,
                  int Mtot, int K, int Nn) {
  const int NT = Nn >> 8;
  const int id = blockIdx.x;
  const int xcd = id & 7;
  const int within = id >> 3;
  const int slot = xcd + 8 * (within / NT);  // m-slot
  const int ntile = within % NT;             // n-tile

  int row_start = 0, tiles_before = 0;
  int expert = -1, my_row0 = 0, rows_valid = 0;
#pragma unroll
  for (int e = 0; e < 8; ++e) {
    int tk = tokens[e];
    int nt = (tk + 255) >> 8;
    if (expert < 0 && slot >= tiles_before && slot < tiles_before + nt) {
      expert = e;
      int mi = slot - tiles_before;
      my_row0 = row_start + mi * 256;
      rows_valid = tk - mi * 256;
      if (rows_valid > 256) rows_valid = 256;
    }
    tiles_before += nt;
    row_start += tk;
  }
  if (expert < 0) return;  // idle slack slot (grid tail; uniform per block, before barriers)

  const int n0 = ntile * 256;
  const u16* Bq = Bt + (size_t)expert * Nn * K + (size_t)n0 * K;

  __shared__ __align__(16) u16 lA[4][8192];  // 4 x 16KB ring (256 rows x 32 k)
  __shared__ __align__(16) u16 lB[4][8192];

  const int tid = threadIdx.x;
  const int lane = tid & 63;
  const int wave = tid >> 6;
  const int wm = (wave >> 2) * 128;  // 2 M-halves
  const int wn = (wave & 3) * 64;    // 4 N-quarters
  const int fr = lane & 15;
  const int fq = lane >> 4;

  f32x4 acc[8][4];
#pragma unroll
  for (int i = 0; i < 8; ++i)
#pragma unroll
    for (int j = 0; j < 4; ++j) acc[i][j] = (f32x4){0.f, 0.f, 0.f, 0.f};

  // staging: thread tid fills slice slot (row = q*128 + (tid>>2), chunk = tid&3)
  // at elem offset q*4096 + tid*8. Source chunk = stored chunk ^ ((row>>1)&3).
  const int sr = tid >> 2;
  const int swz = ((tid & 3) ^ ((sr >> 1) & 3)) * 8;
  int ga0 = my_row0 + sr;        if (ga0 > Mtot - 1) ga0 = Mtot - 1;  // clamp; store-masked
  int ga1 = my_row0 + 128 + sr;  if (ga1 > Mtot - 1) ga1 = Mtot - 1;
  const u16* pA0 = A + (size_t)ga0 * K + swz;
  const u16* pA1 = A + (size_t)ga1 * K + swz;
  const u16* pB0 = Bq + (size_t)sr * K + swz;
  const u16* pB1 = Bq + (size_t)(128 + sr) * K + swz;

  // fragment read: chunk fq of row lives at swizzled chunk (fq ^ ((fr>>1)&3));
  // (row>>1)&3 == (fr>>1)&3 since wm and m*16 are 0 mod 8.
  const int cswz = (fq ^ ((fr >> 1) & 3)) * 8;
  const int aoff0 = (wm + fr) * 32 + cswz;  // + m*16*32
  const int boff0 = (wn + fr) * 32 + cswz;  // + n*16*32

  const int nslices = K >> 5;

  // prologue: stage slices 0,1,2 (4 loads each, in slice order -> vmcnt math uniform)
#pragma unroll
  for (int s = 0; s < 3; ++s) {
    async_ld16(pA0 + s * 32, &lA[s][tid * 8]);
    async_ld16(pA1 + s * 32, &lA[s][4096 + tid * 8]);
    async_ld16(pB0 + s * 32, &lB[s][tid * 8]);
    async_ld16(pB1 + s * 32, &lB[s][4096 + tid * 8]);
  }

  bf16x8 aF[4], bF[4];
  for (int sl = 0; sl < nslices; ++sl) {
    const int b = sl & 3;
    const int nb = (sl + 3) & 3;
    // tail: keep issuing (clamped src) so outstanding-load accounting stays uniform;
    // target buffer (sl-1)&3 is dead (consumed in iter sl-1, never read again).
    const int sk = (sl + 3 < nslices ? sl + 3 : sl) * 32;

    // slices sl+1, sl+2 (8 loads) may stay in flight; slice sl must be done.
    asm volatile("s_waitcnt vmcnt(8)" ::: "memory");
    __builtin_amdgcn_s_barrier();
    asm volatile("" ::: "memory");

    // ---- phase A: stage next-A, compute m-half 0 ----
    async_ld16(pA0 + sk, &lA[nb][tid * 8]);
    async_ld16(pA1 + sk, &lA[nb][4096 + tid * 8]);
#pragma unroll
    for (int n = 0; n < 4; ++n) bF[n] = *(const bf16x8*)&lB[b][boff0 + n * 512];
#pragma unroll
    for (int m = 0; m < 4; ++m) aF[m] = *(const bf16x8*)&lA[b][aoff0 + m * 512];
    __builtin_amdgcn_s_setprio(1);
#pragma unroll
    for (int m = 0; m < 4; ++m)
#pragma unroll
      for (int n = 0; n < 4; ++n)
        acc[m][n] = __builtin_amdgcn_mfma_f32_16x16x32_bf16(aF[m], bF[n], acc[m][n], 0, 0, 0);
    __builtin_amdgcn_s_setprio(0);
    __builtin_amdgcn_s_barrier();
    asm volatile("" ::: "memory");

    // ---- phase B: stage next-B, compute m-half 1 ----
    async_ld16(pB0 + sk, &lB[nb][tid * 8]);
    async_ld16(pB1 + sk, &lB[nb][4096 + tid * 8]);
#pragma unroll
    for (int m = 0; m < 4; ++m) aF[m] = *(const bf16x8*)&lA[b][aoff0 + 2048 + m * 512];
    __builtin_amdgcn_s_setprio(1);
#pragma unroll
    for (int m = 0; m < 4; ++m)
#pragma unroll
      for (int n = 0; n < 4; ++n)
        acc[m + 4][n] = __builtin_amdgcn_mfma_f32_16x16x32_bf16(aF[m], bF[n], acc[m + 4][n], 0, 0, 0);
    __builtin_amdgcn_s_setprio(0);
  }

  // epilogue. C/D layout: col = lane&15, row = (lane>>4)*4 + reg  [m89-verified]
  if (FUSE) {
    u16* Op = (u16*)Out;
#pragma unroll
    for (int m = 0; m < 8; ++m) {
#pragma unroll
      for (int r = 0; r < 4; ++r) {
        int lrow = wm + m * 16 + fq * 4 + r;
        if (lrow < rows_valid) {
          size_t base = (size_t)(my_row0 + lrow) * Nn + (size_t)(n0 + wn + fr);
#pragma unroll
          for (int n = 0; n < 4; ++n)
            Op[base + n * 16] = f32_to_bf16(fast_gelu(acc[m][n][r]));
        }
      }
    }
  } else {
    float* Op = (float*)Out;
#pragma unroll
    for (int m = 0; m < 8; ++m) {
#pragma unroll
      for (int r = 0; r < 4; ++r) {
        int lrow = wm + m * 16 + fq * 4 + r;
        if (lrow < rows_valid) {
          size_t base = (size_t)(my_row0 + lrow) * Nn + (size_t)(n0 + wn + fr);
#pragma unroll
          for (int n = 0; n < 4; ++n) Op[base + n * 16] = acc[m][n][r];
        }
      }
    }
  }
}

extern "C" void kernel_launch(void* const* d_in, const int* in_sizes, int n_in,
                              void* d_out, int out_size, void* d_ws, size_t ws_size,
                              hipStream_t stream) {
  (void)in_sizes; (void)n_in; (void)out_size; (void)ws_size;
  const float* x  = (const float*)d_in[0];   // [N][H]
  const float* w1 = (const float*)d_in[1];   // [E][H][F]
  const float* w2 = (const float*)d_in[2];   // [E][F][H]
  const int* tokens = (const int*)d_in[3];   // [E]

  const int N = 16384, H = 1024, F = 4096, E = 8;

  // ws layout (bf16): x 32MB | w1^T 64MB | w2^T 64MB | intermediate 128MB  (~302 MB)
  u16* x_bf  = (u16*)d_ws;
  u16* w1t   = x_bf + (size_t)N * H;       // [E][F][H]
  u16* w2t   = w1t + (size_t)E * F * H;    // [E][H][F]
  u16* inter = w2t + (size_t)E * H * F;    // [N][F]

  cvt_kernel<<<dim3((N * H / 8 + 255) / 256), dim3(256), 0, stream>>>(x, x_bf, N * H / 8);
  tpose_cvt_kernel<<<dim3(F / 64, H / 64, E), dim3(256), 0, stream>>>(w1, w1t, H, F);
  tpose_cvt_kernel<<<dim3(H / 64, F / 64, E), dim3(256), 0, stream>>>(w2, w2t, F, H);

  const int SLOTS = N / 256 + E;  // 72, divisible by 8 (swizzle requirement)
  // GEMM1: [N][H] x [H][F] -> gelu -> bf16 inter [N][F]
  grouped_gemm<1><<<dim3((F / 256) * SLOTS), dim3(512), 0, stream>>>(
      x_bf, w1t, inter, tokens, N, H, F);
  // GEMM2: [N][F] x [F][H] -> f32 out [N][H]
  grouped_gemm<0><<<dim3((H / 256) * SLOTS), dim3(512), 0, stream>>>(
      inter, w2t, (float*)d_out, tokens, N, F, H);
}